// Round 8
// baseline (115.737 us; speedup 1.0000x reference)
//
#include <hip/hip_runtime.h>
#include <hip/hip_bf16.h>
#include <math.h>

#define EMB 768
#define NB 2
#define NWIN 512
#define NROWS (NB*NWIN)          // 1024
#define SWIN 64
#define HRDIM 32
#define ROWF (NROWS*EMB)         // 786432
#define WELEM (EMB*EMB)          // 589824

using bfrag = __attribute__((ext_vector_type(8))) short;   // 8 bf16 (4 VGPRs)
using f32x4 = __attribute__((ext_vector_type(4))) float;

#define GL16(g, l)  __builtin_amdgcn_global_load_lds(                         \
    (const __attribute__((address_space(1))) void*)(g),                       \
    (__attribute__((address_space(3))) void*)(l), 16, 0, 0)

// ---------------------------------------------------------------------------
// prep kernel: all input conversions + folded bias + ctr reset, ONE launch.
//  blocks [0,960):      fp32->bf16 direct (LR 384, Wq 288, Wo 288)
//  blocks [960,2112):   fp32->bf16 transposed (WkT, WvT; 576 each)
//  blocks [2112,2304):  bvo[p] = bo[p] + sum_n Wo[p][n]*bv[n]  (+ ctr=0)
// ---------------------------------------------------------------------------
__global__ __launch_bounds__(256)
void prep_kernel(const float* __restrict__ LR, __hip_bfloat16* __restrict__ LRb,
                 const float* __restrict__ Wq, __hip_bfloat16* __restrict__ Wqb,
                 const float* __restrict__ Wo, __hip_bfloat16* __restrict__ Wob,
                 const float* __restrict__ Wk, __hip_bfloat16* __restrict__ WkTb,
                 const float* __restrict__ Wv, __hip_bfloat16* __restrict__ WvTb,
                 const float* __restrict__ bv, const float* __restrict__ bo,
                 float* __restrict__ bvo, int* __restrict__ ctr) {
  __shared__ float tile[32][33];
  const int bx = blockIdx.x;
  const int t = threadIdx.x;

  if (bx < 960) {                      // ---- direct converts
    const float* in; __hip_bfloat16* out; int i;
    if (bx < 384)      { in = LR; out = LRb; i = bx * 256 + t; }
    else if (bx < 672) { in = Wq; out = Wqb; i = (bx - 384) * 256 + t; }
    else               { in = Wo; out = Wob; i = (bx - 672) * 256 + t; }
    float4 a = *(const float4*)&in[(size_t)i * 8];
    float4 b = *(const float4*)&in[(size_t)i * 8 + 4];
    __hip_bfloat16 o[8];
    o[0] = __float2bfloat16(a.x); o[1] = __float2bfloat16(a.y);
    o[2] = __float2bfloat16(a.z); o[3] = __float2bfloat16(a.w);
    o[4] = __float2bfloat16(b.x); o[5] = __float2bfloat16(b.y);
    o[6] = __float2bfloat16(b.z); o[7] = __float2bfloat16(b.w);
    *(uint4*)&out[(size_t)i * 8] = *(const uint4*)o;
  } else if (bx < 2112) {              // ---- transposed converts
    int idx = bx - 960;
    int z = idx / 576, rem = idx % 576;
    int bi = rem % 24, bj = rem / 24;
    const float* in; __hip_bfloat16* out;
    if (z == 0) { in = Wk; out = WkTb; }
    else        { in = Wv; out = WvTb; }
    const int c = t & 31, r8 = t >> 5;
#pragma unroll
    for (int rr = 0; rr < 4; ++rr) {
      int r = r8 + rr * 8;
      tile[c][r] = in[(size_t)(bi * 32 + r) * EMB + bj * 32 + c];
    }
    __syncthreads();
#pragma unroll
    for (int rr = 0; rr < 4; ++rr) {
      int n = r8 + rr * 8;
      out[(size_t)(bj * 32 + n) * EMB + bi * 32 + c] = __float2bfloat16(tile[n][c]);
    }
  } else {                             // ---- bvo (f32, exact) + ctr reset
    int idx = bx - 2112;
    if (idx == 0 && t == 0) *ctr = 0;
    const int w = t >> 6, lane = t & 63;
    const int p = idx * 4 + w;
    float s = 0.f;
#pragma unroll
    for (int r = 0; r < 12; ++r) {
      int n = lane + r * 64;
      s = fmaf(Wo[(size_t)p * EMB + n], bv[n], s);
    }
#pragma unroll
    for (int o = 32; o > 0; o >>= 1) s += __shfl_xor(s, o, 64);
    if (lane == 0) bvo[p] = bo[p] + s;
  }
}

// ---------------------------------------------------------------------------
// 128x128 MFMA bf16 GEMM, 3-way z-batched with optional in-launch dependency:
// z=0 blocks signal ctr (release) when done; z=2 blocks acquire-spin until
// ctr==48 before staging (deadlock-free: producers never blocked from CUs).
// C[m][n] = sum_k A[m][k]*B[n][k] (+bias[n]) (+R[m][n]). 4 waves 2x2, 64x64
// per wave. BK=64, K=768 (NT=12, unrolled). 3-deep LDS ring (96 KB) via
// global_load_lds(16B) + counted vmcnt + raw s_barrier. XOR chunk swizzle
// via pre-swizzled global source (linear LDS dest).
// ---------------------------------------------------------------------------
__global__ __launch_bounds__(256)
void gemm128(const __hip_bfloat16* __restrict__ A0,
             const __hip_bfloat16* __restrict__ B0,
             const float* __restrict__ bias0, float* __restrict__ Cf0,
             __hip_bfloat16* __restrict__ Cb0, const float* __restrict__ R0,
             const __hip_bfloat16* __restrict__ A1,
             const __hip_bfloat16* __restrict__ B1,
             const float* __restrict__ bias1, float* __restrict__ Cf1,
             __hip_bfloat16* __restrict__ Cb1,
             const __hip_bfloat16* __restrict__ A2,
             const __hip_bfloat16* __restrict__ B2,
             const float* __restrict__ bias2, float* __restrict__ Cf2,
             __hip_bfloat16* __restrict__ Cb2,
             int* ctr, int N, int ylim1) {
  constexpr int K = EMB;
  constexpr int NT = K / 64;          // 12
  const int zi = blockIdx.z;
  const __hip_bfloat16* A  = (zi == 0) ? A0 : (zi == 1) ? A1 : A2;
  const __hip_bfloat16* Bm = (zi == 0) ? B0 : (zi == 1) ? B1 : B2;
  const float* bias = (zi == 0) ? bias0 : (zi == 1) ? bias1 : bias2;
  float* Cf = (zi == 0) ? Cf0 : (zi == 1) ? Cf1 : Cf2;
  __hip_bfloat16* Cb = (zi == 0) ? Cb0 : (zi == 1) ? Cb1 : Cb2;
  const float* R = (zi == 0) ? R0 : nullptr;

  if (zi == 1 && (int)blockIdx.y >= ylim1) return;

  // consumer blocks: wait for all 48 z=0 producer blocks (device-scope)
  if (ctr && zi == 2) {
    if ((threadIdx.x & 63) == 0) {
      int it = 0;
      while (__hip_atomic_load(ctr, __ATOMIC_ACQUIRE,
                               __HIP_MEMORY_SCOPE_AGENT) < 48 &&
             it < (1 << 20)) {
        __builtin_amdgcn_s_sleep(4);
        ++it;
      }
    }
    __syncthreads();
  }

  __shared__ short lsA[3][128 * 64];  // 3 x 16 KB
  __shared__ short lsB[3][128 * 64];
  const int t = threadIdx.x;
  const int w = t >> 6, lane = t & 63;
  const int lr = lane & 15, lk = lane >> 4;
  const int wr = w >> 1, wc = w & 1;
  const int m0 = blockIdx.y * 128, n0 = blockIdx.x * 128;

  const int r0 = t >> 3;
  const int kc = (t & 7) ^ (r0 & 7);
  const __hip_bfloat16* aptr = A + (size_t)(m0 + r0) * K + kc * 8;
  const __hip_bfloat16* bptr = Bm + (size_t)(n0 + r0) * K + kc * 8;
  const int wb512 = w * 512;

#define STAGE128(sl, ko)                                                      \
  do {                                                                        \
    GL16(aptr + 0 * 32 * K + (ko), &lsA[sl][0 * 2048 + wb512]);               \
    GL16(aptr + 1 * 32 * K + (ko), &lsA[sl][1 * 2048 + wb512]);               \
    GL16(aptr + 2 * 32 * K + (ko), &lsA[sl][2 * 2048 + wb512]);               \
    GL16(aptr + 3 * 32 * K + (ko), &lsA[sl][3 * 2048 + wb512]);               \
    GL16(bptr + 0 * 32 * K + (ko), &lsB[sl][0 * 2048 + wb512]);               \
    GL16(bptr + 1 * 32 * K + (ko), &lsB[sl][1 * 2048 + wb512]);               \
    GL16(bptr + 2 * 32 * K + (ko), &lsB[sl][2 * 2048 + wb512]);               \
    GL16(bptr + 3 * 32 * K + (ko), &lsB[sl][3 * 2048 + wb512]);               \
  } while (0)

  int aoff[4][2], boff[4][2];
#pragma unroll
  for (int f = 0; f < 4; ++f) {
    int ar = wr * 64 + f * 16 + lr;
    int br = wc * 64 + f * 16 + lr;
#pragma unroll
    for (int ks = 0; ks < 2; ++ks) {
      aoff[f][ks] = ar * 64 + ((((ks << 2) | lk) ^ (ar & 7)) << 3);
      boff[f][ks] = br * 64 + ((((ks << 2) | lk) ^ (br & 7)) << 3);
    }
  }

  f32x4 acc[4][4];
#pragma unroll
  for (int i = 0; i < 4; ++i)
#pragma unroll
    for (int j = 0; j < 4; ++j) acc[i][j] = (f32x4){0.f, 0.f, 0.f, 0.f};

  STAGE128(0, 0);
  STAGE128(1, 64);

#pragma unroll
  for (int kt = 0; kt < NT; ++kt) {
    if (kt + 2 < NT) {
      constexpr int s3[NT + 2] = {0,1,2,0,1,2,0,1,2,0,1,2,0,1};
      STAGE128(s3[kt + 2], (kt + 2) * 64);
    }
    if (kt + 2 < NT)      asm volatile("s_waitcnt vmcnt(16)" ::: "memory");
    else if (kt + 1 < NT) asm volatile("s_waitcnt vmcnt(8)" ::: "memory");
    else                  asm volatile("s_waitcnt vmcnt(0)" ::: "memory");
    __builtin_amdgcn_sched_barrier(0);
    __builtin_amdgcn_s_barrier();

    const int cur = kt % 3;
#pragma unroll
    for (int ks = 0; ks < 2; ++ks) {
      bfrag a_[4], b_[4];
#pragma unroll
      for (int f = 0; f < 4; ++f) {
        a_[f] = *(const bfrag*)&lsA[cur][aoff[f][ks]];
        b_[f] = *(const bfrag*)&lsB[cur][boff[f][ks]];
      }
#pragma unroll
      for (int i = 0; i < 4; ++i)
#pragma unroll
        for (int j = 0; j < 4; ++j)
          acc[i][j] = __builtin_amdgcn_mfma_f32_16x16x32_bf16(
              a_[i], b_[j], acc[i][j], 0, 0, 0);
    }

    asm volatile("s_waitcnt lgkmcnt(0)" ::: "memory");
    __builtin_amdgcn_s_barrier();
    __builtin_amdgcn_sched_barrier(0);
  }
#undef STAGE128

  float bs[4];
#pragma unroll
  for (int j = 0; j < 4; ++j)
    bs[j] = bias ? bias[n0 + wc * 64 + j * 16 + lr] : 0.f;

#pragma unroll
  for (int i = 0; i < 4; ++i) {
#pragma unroll
    for (int j = 0; j < 4; ++j) {
      int n = n0 + wc * 64 + j * 16 + lr;           // C col = lane&15
#pragma unroll
      for (int q = 0; q < 4; ++q) {
        int m = m0 + wr * 64 + i * 16 + lk * 4 + q; // C row = (lane>>4)*4+reg
        float v = acc[i][j][q] + bs[j];
        if (R) v += R[(size_t)m * N + n];
        if (Cf) Cf[(size_t)m * N + n] = v;
        if (Cb) Cb[(size_t)m * N + n] = __float2bfloat16(v);
      }
    }
  }

  // producer blocks: make stores device-visible, then signal
  if (ctr && zi == 0) {
    __threadfence();
    __syncthreads();
    if (threadIdx.x == 0)
      __hip_atomic_fetch_add(ctr, 1, __ATOMIC_RELEASE,
                             __HIP_MEMORY_SCOPE_AGENT);
  }
}

// ---------------------------------------------------------------------------
// Attention core, online softmax, single HBM pass over HR, no window buffer.
// 8 waves x 8 rows each; per-row: load -> dot -> wave-reduce -> flash-rescale
// f32 accumulate. Cross-wave combine via 24 KB LDS partials.
// ---------------------------------------------------------------------------
__global__ __launch_bounds__(512)
void attn_kernel(const float* __restrict__ HR, const float* __restrict__ qt,
                 __hip_bfloat16* __restrict__ zb) {
  const int g = blockIdx.x;
  const int b = g >> 9;
  const int n = g & 511;
  const int db = n >> 6, wb = (n >> 3) & 7, hb = n & 7;

  __shared__ float zp[8][EMB];      // per-wave z partials (24 KB)
  __shared__ float ml[8][2];        // per-wave running (m, l)

  const int t = threadIdx.x;
  const int w = t >> 6, lane = t & 63;

  float4 qv[3];
#pragma unroll
  for (int r = 0; r < 3; ++r)
    qv[r] = *(const float4*)&qt[(size_t)g * EMB + (lane + r * 64) * 4];

  const float* rows[8];
#pragma unroll
  for (int i = 0; i < 8; ++i) {
    int s = w * 8 + i;
    int D = db * 4 + (s >> 4), W = wb * 4 + ((s >> 2) & 3), H = hb * 4 + (s & 3);
    rows[i] = HR + (size_t)((((b * HRDIM + D) * HRDIM + W) * HRDIM + H)) * EMB;
  }

  const float scale = 0.036084391824351615f;  // 1/sqrt(768)
  float m = -3.0e38f, l = 0.f;
  float4 z0 = {0,0,0,0}, z1 = {0,0,0,0}, z2 = {0,0,0,0};

  float4 h0 = *(const float4*)&rows[0][lane * 4];
  float4 h1 = *(const float4*)&rows[0][(lane + 64) * 4];
  float4 h2 = *(const float4*)&rows[0][(lane + 128) * 4];

#pragma unroll
  for (int i = 0; i < 8; ++i) {
    float4 n0, n1, n2;
    if (i < 7) {
      n0 = *(const float4*)&rows[i + 1][lane * 4];
      n1 = *(const float4*)&rows[i + 1][(lane + 64) * 4];
      n2 = *(const float4*)&rows[i + 1][(lane + 128) * 4];
    }
    float p = 0.f;
    p = fmaf(h0.x, qv[0].x, p); p = fmaf(h0.y, qv[0].y, p);
    p = fmaf(h0.z, qv[0].z, p); p = fmaf(h0.w, qv[0].w, p);
    p = fmaf(h1.x, qv[1].x, p); p = fmaf(h1.y, qv[1].y, p);
    p = fmaf(h1.z, qv[1].z, p); p = fmaf(h1.w, qv[1].w, p);
    p = fmaf(h2.x, qv[2].x, p); p = fmaf(h2.y, qv[2].y, p);
    p = fmaf(h2.z, qv[2].z, p); p = fmaf(h2.w, qv[2].w, p);
#pragma unroll
    for (int o = 32; o > 0; o >>= 1) p += __shfl_xor(p, o, 64);
    p *= scale;
    float mn = fmaxf(m, p);
    float f = expf(m - mn);         // 0 on first iter (m = -3e38)
    float e = expf(p - mn);
    z0.x = fmaf(e, h0.x, z0.x * f); z0.y = fmaf(e, h0.y, z0.y * f);
    z0.z = fmaf(e, h0.z, z0.z * f); z0.w = fmaf(e, h0.w, z0.w * f);
    z1.x = fmaf(e, h1.x, z1.x * f); z1.y = fmaf(e, h1.y, z1.y * f);
    z1.z = fmaf(e, h1.z, z1.z * f); z1.w = fmaf(e, h1.w, z1.w * f);
    z2.x = fmaf(e, h2.x, z2.x * f); z2.y = fmaf(e, h2.y, z2.y * f);
    z2.z = fmaf(e, h2.z, z2.z * f); z2.w = fmaf(e, h2.w, z2.w * f);
    l = fmaf(l, f, e);
    m = mn;
    if (i < 7) { h0 = n0; h1 = n1; h2 = n2; }
  }

  *(float4*)&zp[w][lane * 4] = z0;
  *(float4*)&zp[w][(lane + 64) * 4] = z1;
  *(float4*)&zp[w][(lane + 128) * 4] = z2;
  if (lane == 0) { ml[w][0] = m; ml[w][1] = l; }
  __syncthreads();

  if (t < 384) {
    float M = -3.0e38f;
#pragma unroll
    for (int w8 = 0; w8 < 8; ++w8) M = fmaxf(M, ml[w8][0]);
    float L = 0.f, a0 = 0.f, a1 = 0.f;
#pragma unroll
    for (int w8 = 0; w8 < 8; ++w8) {
      float ew = expf(ml[w8][0] - M);
      L = fmaf(ml[w8][1], ew, L);
      float2 v = *(const float2*)&zp[w8][t * 2];
      a0 = fmaf(v.x, ew, a0);
      a1 = fmaf(v.y, ew, a1);
    }
    float rl = 1.f / L;
    __hip_bfloat16 o[2];
    o[0] = __float2bfloat16(a0 * rl);
    o[1] = __float2bfloat16(a1 * rl);
    *(unsigned*)&zb[(size_t)g * EMB + t * 2] = *(const unsigned*)o;
  }
}

// ---------------------------------------------------------------------------
// out = LayerNorm(res) * g + b   (res = Q + x precomputed in GEMM epilogue)
// ---------------------------------------------------------------------------
__global__ __launch_bounds__(256)
void ln_kernel(const float* __restrict__ R, const float* __restrict__ gma,
               const float* __restrict__ bta, float* __restrict__ out) {
  const int row = blockIdx.x;
  const int t = threadIdx.x;
  const int wave = t >> 6, lane = t & 63;
  __shared__ float red[4];

  float v[3];
  float s = 0.f;
#pragma unroll
  for (int r = 0; r < 3; ++r) {
    int c = t + r * 256;
    v[r] = R[(size_t)row * EMB + c];
    s += v[r];
  }
#pragma unroll
  for (int o = 32; o > 0; o >>= 1) s += __shfl_xor(s, o, 64);
  if (lane == 0) red[wave] = s;
  __syncthreads();
  float mu = (red[0] + red[1] + red[2] + red[3]) * (1.f / EMB);
  __syncthreads();

  float q = 0.f;
#pragma unroll
  for (int r = 0; r < 3; ++r) {
    float d = v[r] - mu;
    q += d * d;
  }
#pragma unroll
  for (int o = 32; o > 0; o >>= 1) q += __shfl_xor(q, o, 64);
  if (lane == 0) red[wave] = q;
  __syncthreads();
  float var = (red[0] + red[1] + red[2] + red[3]) * (1.f / EMB);
  float inv = rsqrtf(var + 1e-5f);

#pragma unroll
  for (int r = 0; r < 3; ++r) {
    int c = t + r * 256;
    out[(size_t)row * EMB + c] = (v[r] - mu) * inv * gma[c] + bta[c];
  }
}

// ---------------------------------------------------------------------------
extern "C" void kernel_launch(void* const* d_in, const int* in_sizes, int n_in,
                              void* d_out, int out_size, void* d_ws, size_t ws_size,
                              hipStream_t stream) {
  const float* LR  = (const float*)d_in[0];
  const float* HR  = (const float*)d_in[1];
  const float* Wq  = (const float*)d_in[2];
  const float* bq  = (const float*)d_in[3];
  const float* Wk  = (const float*)d_in[4];
  // d_in[5] = Wk_b: softmax-invariant constant -> dropped (exact)
  const float* Wv  = (const float*)d_in[6];
  const float* bv  = (const float*)d_in[7];
  const float* Wo  = (const float*)d_in[8];
  const float* bo  = (const float*)d_in[9];
  const float* lng = (const float*)d_in[10];
  const float* lnb = (const float*)d_in[11];
  float* out = (float*)d_out;

  char* ws = (char*)d_ws;
  float* Qf = (float*)(ws + 0);                        // [1024][768] f32
  float* qt = (float*)(ws + 3145728);                  // [1024][768] f32
  float* x  = (float*)(ws + 6291456);                  // [1024][768] f32 (res)
  __hip_bfloat16* LRb  = (__hip_bfloat16*)(ws +  9437184);
  __hip_bfloat16* zb   = (__hip_bfloat16*)(ws + 11010048);
  __hip_bfloat16* Qbb  = (__hip_bfloat16*)(ws + 12582912);
  __hip_bfloat16* Wqb  = (__hip_bfloat16*)(ws + 14155776);
  __hip_bfloat16* WkTb = (__hip_bfloat16*)(ws + 15335424);
  __hip_bfloat16* WvTb = (__hip_bfloat16*)(ws + 16515072);
  __hip_bfloat16* Wob  = (__hip_bfloat16*)(ws + 17694720);
  __hip_bfloat16* Wvob = (__hip_bfloat16*)(ws + 18874368);
  float* bvo = (float*)(ws + 20054016);                // [768] f32
  int*   ctr = (int*)(ws + 20971520);                  // producer counter

  dim3 blk(256);

  // 1) prep: converts + transposes + bvo + ctr reset (one launch)
  prep_kernel<<<dim3(2304), blk, 0, stream>>>(
      LR, LRb, Wq, Wqb, Wo, Wob, Wk, WkTb, Wv, WvTb, bv, bo, bvo, ctr);

  // 2) mega-GEMM, one launch, in-launch dependency:
  //    z0: Q  = LR(x)Wq^T + bq      -> Qf (f32) + Qbb (bf16); signals ctr
  //    z1: Wvo = Wo (x) WvT^T       -> Wvob (bf16)            (y < 6)
  //    z2: qt = Qb(x)WkT^T          -> qt (f32); spins on ctr==48
  gemm128<<<dim3(6, 8, 3), blk, 0, stream>>>(
      LRb, Wqb, bq, Qf, Qbb, nullptr,
      Wob, WvTb, nullptr, nullptr, Wvob,
      Qbb, WkTb, nullptr, qt, nullptr,
      ctr, EMB, 6);

  // 3) z = softmax(scale * qt . HR) @ HR   (online, HR read once; bf16 out)
  attn_kernel<<<dim3(NROWS), dim3(512), 0, stream>>>(HR, qt, zb);

  // 4) res = z(x)Wvo^T + bvo + Q   (residual fused; f32 out)
  gemm128<<<dim3(6, 8, 1), blk, 0, stream>>>(
      zb, Wvob, bvo, x, nullptr, Qf,
      nullptr, nullptr, nullptr, nullptr, nullptr,
      nullptr, nullptr, nullptr, nullptr, nullptr,
      nullptr, EMB, 6);

  // 5) out = LN(res) * g + b
  ln_kernel<<<dim3(NROWS), blk, 0, stream>>>(x, lng, lnb, out);
}

// Round 9
// 75.213 us; speedup vs baseline: 1.5388x; 1.5388x over previous
//
#include <hip/hip_runtime.h>
#include <hip/hip_bf16.h>
#include <math.h>

#define EMB 768
#define NB 2
#define NWIN 512
#define NROWS (NB*NWIN)          // 1024
#define SWIN 64
#define HRDIM 32
#define ROWF (NROWS*EMB)         // 786432
#define WELEM (EMB*EMB)          // 589824

using bfrag = __attribute__((ext_vector_type(8))) short;   // 8 bf16 (4 VGPRs)
using f32x4 = __attribute__((ext_vector_type(4))) float;

#define GL16(g, l)  __builtin_amdgcn_global_load_lds(                         \
    (const __attribute__((address_space(1))) void*)(g),                       \
    (__attribute__((address_space(3))) void*)(l), 16, 0, 0)

// ---------------------------------------------------------------------------
// prep kernel: all input conversions + folded bias, ONE launch.
//  blocks [0,960):      fp32->bf16 direct (LR 384, Wq 288, Wo 288)
//  blocks [960,2112):   fp32->bf16 transposed (WkT, WvT; 576 each)
//  blocks [2112,2304):  bvo[p] = bo[p] + sum_n Wo[p][n]*bv[n]
// ---------------------------------------------------------------------------
__global__ __launch_bounds__(256)
void prep_kernel(const float* __restrict__ LR, __hip_bfloat16* __restrict__ LRb,
                 const float* __restrict__ Wq, __hip_bfloat16* __restrict__ Wqb,
                 const float* __restrict__ Wo, __hip_bfloat16* __restrict__ Wob,
                 const float* __restrict__ Wk, __hip_bfloat16* __restrict__ WkTb,
                 const float* __restrict__ Wv, __hip_bfloat16* __restrict__ WvTb,
                 const float* __restrict__ bv, const float* __restrict__ bo,
                 float* __restrict__ bvo) {
  __shared__ float tile[32][33];
  const int bx = blockIdx.x;
  const int t = threadIdx.x;

  if (bx < 960) {                      // ---- direct converts
    const float* in; __hip_bfloat16* out; int i;
    if (bx < 384)      { in = LR; out = LRb; i = bx * 256 + t; }
    else if (bx < 672) { in = Wq; out = Wqb; i = (bx - 384) * 256 + t; }
    else               { in = Wo; out = Wob; i = (bx - 672) * 256 + t; }
    float4 a = *(const float4*)&in[(size_t)i * 8];
    float4 b = *(const float4*)&in[(size_t)i * 8 + 4];
    __hip_bfloat16 o[8];
    o[0] = __float2bfloat16(a.x); o[1] = __float2bfloat16(a.y);
    o[2] = __float2bfloat16(a.z); o[3] = __float2bfloat16(a.w);
    o[4] = __float2bfloat16(b.x); o[5] = __float2bfloat16(b.y);
    o[6] = __float2bfloat16(b.z); o[7] = __float2bfloat16(b.w);
    *(uint4*)&out[(size_t)i * 8] = *(const uint4*)o;
  } else if (bx < 2112) {              // ---- transposed converts
    int idx = bx - 960;
    int z = idx / 576, rem = idx % 576;
    int bi = rem % 24, bj = rem / 24;
    const float* in; __hip_bfloat16* out;
    if (z == 0) { in = Wk; out = WkTb; }
    else        { in = Wv; out = WvTb; }
    const int c = t & 31, r8 = t >> 5;
#pragma unroll
    for (int rr = 0; rr < 4; ++rr) {
      int r = r8 + rr * 8;
      tile[c][r] = in[(size_t)(bi * 32 + r) * EMB + bj * 32 + c];
    }
    __syncthreads();
#pragma unroll
    for (int rr = 0; rr < 4; ++rr) {
      int n = r8 + rr * 8;
      out[(size_t)(bj * 32 + n) * EMB + bi * 32 + c] = __float2bfloat16(tile[n][c]);
    }
  } else {                             // ---- bvo (f32, exact)
    int idx = bx - 2112;
    const int w = t >> 6, lane = t & 63;
    const int p = idx * 4 + w;
    float s = 0.f;
#pragma unroll
    for (int r = 0; r < 12; ++r) {
      int n = lane + r * 64;
      s = fmaf(Wo[(size_t)p * EMB + n], bv[n], s);
    }
#pragma unroll
    for (int o = 32; o > 0; o >>= 1) s += __shfl_xor(s, o, 64);
    if (lane == 0) bvo[p] = bo[p] + s;
  }
}

// ---------------------------------------------------------------------------
// 64x64 MFMA bf16 GEMM, 2-way z-batched: C[m][n] = sum_k A[m][k]*B[n][k]
// (+bias[n]) (+R[m][n]); outputs f32 (Cf) and/or bf16 (Cb), null-guarded.
// 4 waves, BK=64, K=768 (NT=12, unrolled). 3-deep LDS ring (48 KB -> ~3
// blocks/CU co-resident) staged by global_load_lds(16B) + counted vmcnt +
// raw s_barrier. XOR chunk swizzle via pre-swizzled global source.
// ---------------------------------------------------------------------------
__global__ __launch_bounds__(256)
void gemm64(const __hip_bfloat16* __restrict__ A0,
            const __hip_bfloat16* __restrict__ B0,
            const float* __restrict__ bias0, float* __restrict__ Cf0,
            __hip_bfloat16* __restrict__ Cb0, const float* __restrict__ R0,
            const __hip_bfloat16* __restrict__ A1,
            const __hip_bfloat16* __restrict__ B1,
            const float* __restrict__ bias1, float* __restrict__ Cf1,
            __hip_bfloat16* __restrict__ Cb1,
            int N, int ylim1) {
  constexpr int K = EMB;
  constexpr int NT = K / 64;          // 12
  const int zi = blockIdx.z;
  const __hip_bfloat16* A  = zi ? A1 : A0;
  const __hip_bfloat16* Bm = zi ? B1 : B0;
  const float* bias = zi ? bias1 : bias0;
  float* Cf = zi ? Cf1 : Cf0;
  __hip_bfloat16* Cb = zi ? Cb1 : Cb0;
  const float* R = zi ? nullptr : R0;

  if (zi == 1 && (int)blockIdx.y >= ylim1) return;

  __shared__ short lsA[3][64 * 64];   // 3 x 8 KB ring
  __shared__ short lsB[3][64 * 64];
  const int t = threadIdx.x;
  const int w = t >> 6, lane = t & 63;
  const int lr = lane & 15, lk = lane >> 4;
  const int m0 = blockIdx.y * 64, n0 = blockIdx.x * 64;

  const int r0 = t >> 3, c0 = t & 7;
  const int kc = c0 ^ (r0 & 7);
  const __hip_bfloat16* aptr0 = A + (size_t)(m0 + r0) * K + kc * 8;
  const __hip_bfloat16* aptr1 = A + (size_t)(m0 + r0 + 32) * K + kc * 8;
  const __hip_bfloat16* bptr0 = Bm + (size_t)(n0 + r0) * K + kc * 8;
  const __hip_bfloat16* bptr1 = Bm + (size_t)(n0 + r0 + 32) * K + kc * 8;
  const int wbase = w * 512;

  const int arow = w * 16 + lr;
  int aoff[2], boff[4][2];
#pragma unroll
  for (int ks = 0; ks < 2; ++ks)
    aoff[ks] = arow * 64 + (((ks << 2) | lk) ^ (arow & 7)) * 8;
#pragma unroll
  for (int f = 0; f < 4; ++f) {
    int br = f * 16 + lr;
#pragma unroll
    for (int ks = 0; ks < 2; ++ks)
      boff[f][ks] = br * 64 + (((ks << 2) | lk) ^ (br & 7)) * 8;
  }

  f32x4 acc[4];
#pragma unroll
  for (int f = 0; f < 4; ++f) acc[f] = (f32x4){0.f, 0.f, 0.f, 0.f};

#pragma unroll
  for (int p = 0; p < 2; ++p) {
    int ko = p * 64;
    GL16(aptr0 + ko, &lsA[p][wbase]);
    GL16(aptr1 + ko, &lsA[p][wbase + 2048]);
    GL16(bptr0 + ko, &lsB[p][wbase]);
    GL16(bptr1 + ko, &lsB[p][wbase + 2048]);
  }

#pragma unroll
  for (int kt = 0; kt < NT; ++kt) {
    if (kt + 2 < NT) {
      constexpr int s3[NT + 2] = {0,1,2,0,1,2,0,1,2,0,1,2,0,1};
      const int sl = s3[kt + 2];
      int ko = (kt + 2) * 64;
      GL16(aptr0 + ko, &lsA[sl][wbase]);
      GL16(aptr1 + ko, &lsA[sl][wbase + 2048]);
      GL16(bptr0 + ko, &lsB[sl][wbase]);
      GL16(bptr1 + ko, &lsB[sl][wbase + 2048]);
    }
    if (kt + 2 < NT)      asm volatile("s_waitcnt vmcnt(8)" ::: "memory");
    else if (kt + 1 < NT) asm volatile("s_waitcnt vmcnt(4)" ::: "memory");
    else                  asm volatile("s_waitcnt vmcnt(0)" ::: "memory");
    __builtin_amdgcn_sched_barrier(0);
    __builtin_amdgcn_s_barrier();

    const int cur = kt % 3;
    bfrag a0 = *(const bfrag*)&lsA[cur][aoff[0]];
    bfrag a1 = *(const bfrag*)&lsA[cur][aoff[1]];
    bfrag b00 = *(const bfrag*)&lsB[cur][boff[0][0]];
    bfrag b01 = *(const bfrag*)&lsB[cur][boff[0][1]];
    bfrag b10 = *(const bfrag*)&lsB[cur][boff[1][0]];
    bfrag b11 = *(const bfrag*)&lsB[cur][boff[1][1]];
    bfrag b20 = *(const bfrag*)&lsB[cur][boff[2][0]];
    bfrag b21 = *(const bfrag*)&lsB[cur][boff[2][1]];
    bfrag b30 = *(const bfrag*)&lsB[cur][boff[3][0]];
    bfrag b31 = *(const bfrag*)&lsB[cur][boff[3][1]];
    acc[0] = __builtin_amdgcn_mfma_f32_16x16x32_bf16(a0, b00, acc[0], 0, 0, 0);
    acc[0] = __builtin_amdgcn_mfma_f32_16x16x32_bf16(a1, b01, acc[0], 0, 0, 0);
    acc[1] = __builtin_amdgcn_mfma_f32_16x16x32_bf16(a0, b10, acc[1], 0, 0, 0);
    acc[1] = __builtin_amdgcn_mfma_f32_16x16x32_bf16(a1, b11, acc[1], 0, 0, 0);
    acc[2] = __builtin_amdgcn_mfma_f32_16x16x32_bf16(a0, b20, acc[2], 0, 0, 0);
    acc[2] = __builtin_amdgcn_mfma_f32_16x16x32_bf16(a1, b21, acc[2], 0, 0, 0);
    acc[3] = __builtin_amdgcn_mfma_f32_16x16x32_bf16(a0, b30, acc[3], 0, 0, 0);
    acc[3] = __builtin_amdgcn_mfma_f32_16x16x32_bf16(a1, b31, acc[3], 0, 0, 0);

    asm volatile("s_waitcnt lgkmcnt(0)" ::: "memory");
    __builtin_amdgcn_s_barrier();
    __builtin_amdgcn_sched_barrier(0);
  }

  float bs[4];
#pragma unroll
  for (int f = 0; f < 4; ++f)
    bs[f] = bias ? bias[n0 + f * 16 + lr] : 0.f;

#pragma unroll
  for (int f = 0; f < 4; ++f) {
    int n = n0 + f * 16 + lr;                        // C col = lane&15
#pragma unroll
    for (int j = 0; j < 4; ++j) {
      int m = m0 + w * 16 + lk * 4 + j;              // C row = (lane>>4)*4+reg
      float v = acc[f][j] + bs[f];
      if (R)  v += R[(size_t)m * N + n];
      if (Cf) Cf[(size_t)m * N + n] = v;
      if (Cb) Cb[(size_t)m * N + n] = __float2bfloat16(v);
    }
  }
}

// ---------------------------------------------------------------------------
// Attention core, online softmax, single HBM pass over HR, no window buffer.
// 8 waves x 8 rows each; per-row: load -> dot -> wave-reduce -> flash-rescale
// f32 accumulate. Cross-wave combine via 24 KB LDS partials.
// ---------------------------------------------------------------------------
__global__ __launch_bounds__(512)
void attn_kernel(const float* __restrict__ HR, const float* __restrict__ qt,
                 __hip_bfloat16* __restrict__ zb) {
  const int g = blockIdx.x;
  const int b = g >> 9;
  const int n = g & 511;
  const int db = n >> 6, wb = (n >> 3) & 7, hb = n & 7;

  __shared__ float zp[8][EMB];      // per-wave z partials (24 KB)
  __shared__ float ml[8][2];        // per-wave running (m, l)

  const int t = threadIdx.x;
  const int w = t >> 6, lane = t & 63;

  float4 qv[3];
#pragma unroll
  for (int r = 0; r < 3; ++r)
    qv[r] = *(const float4*)&qt[(size_t)g * EMB + (lane + r * 64) * 4];

  const float* rows[8];
#pragma unroll
  for (int i = 0; i < 8; ++i) {
    int s = w * 8 + i;
    int D = db * 4 + (s >> 4), W = wb * 4 + ((s >> 2) & 3), H = hb * 4 + (s & 3);
    rows[i] = HR + (size_t)((((b * HRDIM + D) * HRDIM + W) * HRDIM + H)) * EMB;
  }

  const float scale = 0.036084391824351615f;  // 1/sqrt(768)
  float m = -3.0e38f, l = 0.f;
  float4 z0 = {0,0,0,0}, z1 = {0,0,0,0}, z2 = {0,0,0,0};

  float4 h0 = *(const float4*)&rows[0][lane * 4];
  float4 h1 = *(const float4*)&rows[0][(lane + 64) * 4];
  float4 h2 = *(const float4*)&rows[0][(lane + 128) * 4];

#pragma unroll
  for (int i = 0; i < 8; ++i) {
    float4 n0, n1, n2;
    if (i < 7) {
      n0 = *(const float4*)&rows[i + 1][lane * 4];
      n1 = *(const float4*)&rows[i + 1][(lane + 64) * 4];
      n2 = *(const float4*)&rows[i + 1][(lane + 128) * 4];
    }
    float p = 0.f;
    p = fmaf(h0.x, qv[0].x, p); p = fmaf(h0.y, qv[0].y, p);
    p = fmaf(h0.z, qv[0].z, p); p = fmaf(h0.w, qv[0].w, p);
    p = fmaf(h1.x, qv[1].x, p); p = fmaf(h1.y, qv[1].y, p);
    p = fmaf(h1.z, qv[1].z, p); p = fmaf(h1.w, qv[1].w, p);
    p = fmaf(h2.x, qv[2].x, p); p = fmaf(h2.y, qv[2].y, p);
    p = fmaf(h2.z, qv[2].z, p); p = fmaf(h2.w, qv[2].w, p);
#pragma unroll
    for (int o = 32; o > 0; o >>= 1) p += __shfl_xor(p, o, 64);
    p *= scale;
    float mn = fmaxf(m, p);
    float f = expf(m - mn);         // 0 on first iter (m = -3e38)
    float e = expf(p - mn);
    z0.x = fmaf(e, h0.x, z0.x * f); z0.y = fmaf(e, h0.y, z0.y * f);
    z0.z = fmaf(e, h0.z, z0.z * f); z0.w = fmaf(e, h0.w, z0.w * f);
    z1.x = fmaf(e, h1.x, z1.x * f); z1.y = fmaf(e, h1.y, z1.y * f);
    z1.z = fmaf(e, h1.z, z1.z * f); z1.w = fmaf(e, h1.w, z1.w * f);
    z2.x = fmaf(e, h2.x, z2.x * f); z2.y = fmaf(e, h2.y, z2.y * f);
    z2.z = fmaf(e, h2.z, z2.z * f); z2.w = fmaf(e, h2.w, z2.w * f);
    l = fmaf(l, f, e);
    m = mn;
    if (i < 7) { h0 = n0; h1 = n1; h2 = n2; }
  }

  *(float4*)&zp[w][lane * 4] = z0;
  *(float4*)&zp[w][(lane + 64) * 4] = z1;
  *(float4*)&zp[w][(lane + 128) * 4] = z2;
  if (lane == 0) { ml[w][0] = m; ml[w][1] = l; }
  __syncthreads();

  if (t < 384) {
    float M = -3.0e38f;
#pragma unroll
    for (int w8 = 0; w8 < 8; ++w8) M = fmaxf(M, ml[w8][0]);
    float L = 0.f, a0 = 0.f, a1 = 0.f;
#pragma unroll
    for (int w8 = 0; w8 < 8; ++w8) {
      float ew = expf(ml[w8][0] - M);
      L = fmaf(ml[w8][1], ew, L);
      float2 v = *(const float2*)&zp[w8][t * 2];
      a0 = fmaf(v.x, ew, a0);
      a1 = fmaf(v.y, ew, a1);
    }
    float rl = 1.f / L;
    __hip_bfloat16 o[2];
    o[0] = __float2bfloat16(a0 * rl);
    o[1] = __float2bfloat16(a1 * rl);
    *(unsigned*)&zb[(size_t)g * EMB + t * 2] = *(const unsigned*)o;
  }
}

// ---------------------------------------------------------------------------
// out = LayerNorm(res) * g + b   (res = Q + x precomputed in GEMM epilogue)
// ---------------------------------------------------------------------------
__global__ __launch_bounds__(256)
void ln_kernel(const float* __restrict__ R, const float* __restrict__ gma,
               const float* __restrict__ bta, float* __restrict__ out) {
  const int row = blockIdx.x;
  const int t = threadIdx.x;
  const int wave = t >> 6, lane = t & 63;
  __shared__ float red[4];

  float v[3];
  float s = 0.f;
#pragma unroll
  for (int r = 0; r < 3; ++r) {
    int c = t + r * 256;
    v[r] = R[(size_t)row * EMB + c];
    s += v[r];
  }
#pragma unroll
  for (int o = 32; o > 0; o >>= 1) s += __shfl_xor(s, o, 64);
  if (lane == 0) red[wave] = s;
  __syncthreads();
  float mu = (red[0] + red[1] + red[2] + red[3]) * (1.f / EMB);
  __syncthreads();

  float q = 0.f;
#pragma unroll
  for (int r = 0; r < 3; ++r) {
    float d = v[r] - mu;
    q += d * d;
  }
#pragma unroll
  for (int o = 32; o > 0; o >>= 1) q += __shfl_xor(q, o, 64);
  if (lane == 0) red[wave] = q;
  __syncthreads();
  float var = (red[0] + red[1] + red[2] + red[3]) * (1.f / EMB);
  float inv = rsqrtf(var + 1e-5f);

#pragma unroll
  for (int r = 0; r < 3; ++r) {
    int c = t + r * 256;
    out[(size_t)row * EMB + c] = (v[r] - mu) * inv * gma[c] + bta[c];
  }
}

// ---------------------------------------------------------------------------
extern "C" void kernel_launch(void* const* d_in, const int* in_sizes, int n_in,
                              void* d_out, int out_size, void* d_ws, size_t ws_size,
                              hipStream_t stream) {
  const float* LR  = (const float*)d_in[0];
  const float* HR  = (const float*)d_in[1];
  const float* Wq  = (const float*)d_in[2];
  const float* bq  = (const float*)d_in[3];
  const float* Wk  = (const float*)d_in[4];
  // d_in[5] = Wk_b: softmax-invariant constant -> dropped (exact)
  const float* Wv  = (const float*)d_in[6];
  const float* bv  = (const float*)d_in[7];
  const float* Wo  = (const float*)d_in[8];
  const float* bo  = (const float*)d_in[9];
  const float* lng = (const float*)d_in[10];
  const float* lnb = (const float*)d_in[11];
  float* out = (float*)d_out;

  char* ws = (char*)d_ws;
  float* Qf = (float*)(ws + 0);                        // [1024][768] f32
  float* qt = (float*)(ws + 3145728);                  // [1024][768] f32
  float* x  = (float*)(ws + 6291456);                  // [1024][768] f32 (res)
  __hip_bfloat16* LRb  = (__hip_bfloat16*)(ws +  9437184);
  __hip_bfloat16* zb   = (__hip_bfloat16*)(ws + 11010048);
  __hip_bfloat16* Qbb  = (__hip_bfloat16*)(ws + 12582912);
  __hip_bfloat16* Wqb  = (__hip_bfloat16*)(ws + 14155776);
  __hip_bfloat16* WkTb = (__hip_bfloat16*)(ws + 15335424);
  __hip_bfloat16* WvTb = (__hip_bfloat16*)(ws + 16515072);
  __hip_bfloat16* Wob  = (__hip_bfloat16*)(ws + 17694720);
  __hip_bfloat16* Wvob = (__hip_bfloat16*)(ws + 18874368);
  float* bvo = (float*)(ws + 20054016);                // [768] f32

  dim3 blk(256);

  // 1) prep: converts + transposes + bvo (one launch)
  prep_kernel<<<dim3(2304), blk, 0, stream>>>(
      LR, LRb, Wq, Wqb, Wo, Wob, Wk, WkTb, Wv, WvTb, bv, bo, bvo);

  // 2) z0: Q = LR(x)Wq^T + bq -> Qf + Qbb ;  z1: Wvo = Wo(x)WvT^T -> Wvob
  gemm64<<<dim3(12, 16, 2), blk, 0, stream>>>(
      LRb, Wqb, bq, Qf, Qbb, nullptr,
      Wob, WvTb, nullptr, nullptr, Wvob,
      EMB, 12);

  // 3) qt = Qb(x)WkT^T  (f32 out)
  gemm64<<<dim3(12, 16, 1), blk, 0, stream>>>(
      Qbb, WkTb, nullptr, qt, nullptr, nullptr,
      nullptr, nullptr, nullptr, nullptr, nullptr,
      EMB, 0);

  // 4) z = softmax(scale * qt . HR) @ HR   (online, HR read once; bf16 out)
  attn_kernel<<<dim3(NROWS), dim3(512), 0, stream>>>(HR, qt, zb);

  // 5) res = z(x)Wvo^T + bvo + Q   (residual fused; f32 out)
  gemm64<<<dim3(12, 16, 1), blk, 0, stream>>>(
      zb, Wvob, bvo, x, nullptr, Qf,
      nullptr, nullptr, nullptr, nullptr, nullptr,
      EMB, 0);

  // 6) out = LN(res) * g + b
  ln_kernel<<<dim3(NROWS), blk, 0, stream>>>(x, lng, lnb, out);
}